// Round 5
// baseline (750.000 us; speedup 1.0000x reference)
//
#include <hip/hip_runtime.h>
#include <hip/hip_bf16.h>
#include <math.h>

#define T_TOK 4096
#define HID   4096
#define NHQ   32
#define NKVH  8
#define HDIM  128
#define SEQ   1024
#define NBATCH 4

typedef __attribute__((ext_vector_type(8))) short bf16x8;
typedef __attribute__((ext_vector_type(4))) float f32x4;

__device__ __forceinline__ unsigned short f2bf(float f) {
  union { float f; unsigned int u; } x; x.f = f;
  unsigned int r = x.u + 0x7FFFu + ((x.u >> 16) & 1u);
  return (unsigned short)(r >> 16);
}

// async global->LDS, 16B per lane. LDS dest must be wave-uniform base; HW adds lane*16.
#define GLOAD_LDS16(gp, lp)                                                        \
  __builtin_amdgcn_global_load_lds(                                                \
      (__attribute__((address_space(1))) void*)(unsigned long long)(const void*)(gp), \
      (__attribute__((address_space(3))) void*)(unsigned long long)(const void*)(lp), \
      16, 0, 0)

// ---------------- single fused cast fp32 -> bf16 for all 5 tensors -------------
__global__ __launch_bounds__(256) void cast_all_k(const float* __restrict__ x,
                                                  const float* __restrict__ wq,
                                                  const float* __restrict__ wk,
                                                  const float* __restrict__ wv,
                                                  const float* __restrict__ wo,
                                                  unsigned short* __restrict__ xb,
                                                  unsigned short* __restrict__ wqkv,
                                                  unsigned short* __restrict__ wob) {
  int i = blockIdx.x * 256 + threadIdx.x;  // float4 index, total 14680064
  const float* src; unsigned short* dst; int off;
  if (i < 4194304)       { src = x;  dst = xb;   off = i; }
  else if (i < 8388608)  { src = wq; dst = wqkv; off = i - 4194304; }
  else if (i < 9437184)  { src = wk; dst = wqkv + 16777216; off = i - 8388608; }
  else if (i < 10485760) { src = wv; dst = wqkv + 20971520; off = i - 9437184; }
  else                   { src = wo; dst = wob;  off = i - 10485760; }
  float4 f = ((const float4*)src)[off];
  ushort4 o;
  o.x = f2bf(f.x); o.y = f2bf(f.y); o.z = f2bf(f.z); o.w = f2bf(f.w);
  ((ushort4*)dst)[off] = o;
}

// ============== QKV GEMM (fused RoPE): C[4096,6144] = A @ B^T ==================
// Tile 256x128, BK=64, 8 waves (4M x 2N), 16x16x32 MFMA, ring-3 LDS both mats.
// PHASE-SPLIT schedule (m201 template): per K-tile two phases, each
// {8 ds_read || G-loads -> s_barrier -> lgkmcnt(0) -> setprio+16 MFMA -> barrier}.
// vmcnt(6) once per tile (end of P2): retires exactly tile t+1's 6 loads,
// keeps tile t+2's 6 in flight. Swizzle verified 0-conflict (R3).
__global__ __launch_bounds__(512, 2) void gemm_qkv(const unsigned short* __restrict__ A,
                                                   const unsigned short* __restrict__ B,
                                                   const int* __restrict__ pos,
                                                   unsigned short* __restrict__ qr,
                                                   unsigned short* __restrict__ kr,
                                                   unsigned short* __restrict__ vbuf) {
  const int K = 4096, nt = 64;
  __shared__ unsigned short AS[3][16384];  // 96 KB: [256 rows][64 shorts] per slot
  __shared__ unsigned short BS[3][8192];   // 48 KB: [128 rows][64 shorts] per slot
  const int tid  = threadIdx.x;
  const int lane = tid & 63;
  const int wave = tid >> 6;
  const int m16  = lane & 15;
  const int quad = lane >> 4;
  const int wm   = wave >> 1;   // 0..3: rows wm*64..+63
  const int wn   = wave & 1;    // 0..1

  // XCD-aware swizzle (nwg = 768, %8==0)
  const int gx = 48;
  const int orig = blockIdx.y * gx + blockIdx.x;
  const int swz = (orig & 7) * 96 + (orig >> 3);
  const long rowBase = (long)(swz / gx) * 256;
  const long colBase = (long)(swz % gx) * 128;

  // loop-invariant LDS read offsets (shorts): row=base+m16, slot=(ks*4+quad)^(m16&7)
  int aoff[2], boff[2];
#pragma unroll
  for (int ks = 0; ks < 2; ++ks) {
    int sx = ((ks * 4 + quad) ^ (m16 & 7)) * 8;
    aoff[ks] = (wm * 64 + m16) * 64 + sx;
    boff[ks] = (wn * 32 + m16) * 64 + sx;
  }

  // staging source (inverse swizzle), R3-verified
  const long Kl = K;
  const int sck = ((tid & 7) ^ ((tid >> 3) & 7)) * 8;
  const unsigned short* gA = A + (rowBase + (tid >> 3)) * Kl + sck;
  const unsigned short* gB = B + (colBase + (tid >> 3)) * Kl + sck;
  const int dofs = wave * 512;

#define STG_B(slot_, ko_) { GLOAD_LDS16(gB + (ko_),            &BS[slot_][dofs]);         \
                            GLOAD_LDS16(gB + (ko_) + 64 * Kl,  &BS[slot_][4096 + dofs]); }
#define STG_A(slot_, ko_) { GLOAD_LDS16(gA + (ko_),            &AS[slot_][dofs]);         \
                            GLOAD_LDS16(gA + (ko_) + 64 * Kl,  &AS[slot_][4096 + dofs]);  \
                            GLOAD_LDS16(gA + (ko_) + 128 * Kl, &AS[slot_][8192 + dofs]);  \
                            GLOAD_LDS16(gA + (ko_) + 192 * Kl, &AS[slot_][12288 + dofs]); }

  f32x4 acc[4][4] = {};   // [mf][nf]

  // prologue: stage tiles 0 (slot 0) and 1 (slot 1); 6 loads each
  STG_A(0, 0); STG_B(0, 0);
  STG_A(1, 64); STG_B(1, 64);
  asm volatile("s_waitcnt vmcnt(6)" ::: "memory");   // tile0 landed, tile1 in flight
  __builtin_amdgcn_s_barrier();

  for (int g = 0; g < 22; ++g) {
#pragma unroll
    for (int u = 0; u < 3; ++u) {
      const int t = g * 3 + u;
      if (t < nt) {
        const bool doStage = (t + 2) < nt;
        const long kn = (long)(t + 2) * 64;
        bf16x8 af[4], bfr[4];

        // ---------- P1: ks=0 (8 ds_read) || stage A(t+2) ----------
#pragma unroll
        for (int mf = 0; mf < 4; ++mf)
          af[mf] = *(const bf16x8*)(&AS[u][aoff[0] + mf * 1024]);
#pragma unroll
        for (int nf = 0; nf < 4; ++nf)
          bfr[nf] = *(const bf16x8*)(&BS[u][boff[0] + (nf & 1) * 1024 + (nf >> 1) * 4096]);
        if (doStage) STG_A((u + 2) % 3, kn);
        __builtin_amdgcn_s_barrier();
        asm volatile("s_waitcnt lgkmcnt(0)" ::: "memory");
        __builtin_amdgcn_s_setprio(1);
#pragma unroll
        for (int mf = 0; mf < 4; ++mf)
#pragma unroll
          for (int nf = 0; nf < 4; ++nf)
            acc[mf][nf] = __builtin_amdgcn_mfma_f32_16x16x32_bf16(af[mf], bfr[nf], acc[mf][nf], 0, 0, 0);
        __builtin_amdgcn_s_setprio(0);
        __builtin_amdgcn_s_barrier();

        // ---------- P2: ks=1 (8 ds_read) || stage B(t+2), vmcnt(6) ----------
#pragma unroll
        for (int mf = 0; mf < 4; ++mf)
          af[mf] = *(const bf16x8*)(&AS[u][aoff[1] + mf * 1024]);
#pragma unroll
        for (int nf = 0; nf < 4; ++nf)
          bfr[nf] = *(const bf16x8*)(&BS[u][boff[1] + (nf & 1) * 1024 + (nf >> 1) * 4096]);
        if (doStage) STG_B((u + 2) % 3, kn);
        __builtin_amdgcn_s_barrier();
        asm volatile("s_waitcnt lgkmcnt(0)" ::: "memory");
        __builtin_amdgcn_s_setprio(1);
#pragma unroll
        for (int mf = 0; mf < 4; ++mf)
#pragma unroll
          for (int nf = 0; nf < 4; ++nf)
            acc[mf][nf] = __builtin_amdgcn_mfma_f32_16x16x32_bf16(af[mf], bfr[nf], acc[mf][nf], 0, 0, 0);
        __builtin_amdgcn_s_setprio(0);
        if (doStage)         asm volatile("s_waitcnt vmcnt(6)" ::: "memory");
        else if (t + 1 < nt) asm volatile("s_waitcnt vmcnt(0)" ::: "memory");
        __builtin_amdgcn_s_barrier();
      }
    }
  }

  // ---- fused epilogue: RoPE (q/k) or plain (v), bf16 scatter ----
  const int n0 = (int)colBase;   // 128-aligned head window
  unsigned short* dst;
  int rstride, colofs;
  bool dorope;
  if (n0 < 4096)       { dst = qr;   rstride = NHQ * HDIM;  colofs = n0;        dorope = true; }
  else if (n0 < 5120)  { dst = kr;   rstride = NKVH * HDIM; colofs = n0 - 4096; dorope = true; }
  else                 { dst = vbuf; rstride = NKVH * HDIM; colofs = n0 - 5120; dorope = false; }
  const float c0 = -13.287712379549449f / 64.0f;  // -log2(10000)/64
  float fA[2], fB[2];
#pragma unroll
  for (int e = 0; e < 2; ++e) {
    int d = wn * 32 + e * 16 + m16;
    fA[e] = exp2f(c0 * (float)(d >> 1));
    fB[e] = exp2f(c0 * (float)((d >> 1) + 32));
  }
#pragma unroll
  for (int mf = 0; mf < 4; ++mf) {
#pragma unroll
    for (int reg = 0; reg < 4; ++reg) {
      int grow = (int)rowBase + wm * 64 + mf * 16 + quad * 4 + reg;
      unsigned short* drow = dst + (long)grow * rstride + colofs;
      if (dorope) {
        int p = pos[grow];
        p = p < 0 ? 0 : (p > SEQ - 1 ? SEQ - 1 : p);
        float pf = (float)p;
#pragma unroll
        for (int e = 0; e < 2; ++e) {
          int d = wn * 32 + e * 16 + m16;
          float lo = acc[mf][e][reg], hi = acc[mf][e + 2][reg];
          float s1, cc1, s2, cc2;
          __sincosf(pf * fA[e], &s1, &cc1);
          __sincosf(pf * fB[e], &s2, &cc2);
          drow[d]      = f2bf(lo * cc1 - hi * s1);
          drow[d + 64] = f2bf(hi * cc2 + lo * s2);
        }
      } else {
#pragma unroll
        for (int e = 0; e < 2; ++e) {
          int d = wn * 32 + e * 16 + m16;
          drow[d]      = f2bf(acc[mf][e][reg]);
          drow[d + 64] = f2bf(acc[mf][e + 2][reg]);
        }
      }
    }
  }
}

// ============== Output-proj GEMM: C[4096,4096] f32 = A @ B^T ===================
// Tile 256x256, BK=32, 8 waves (2M x 4N), per-wave 128x64 (m201 intensity).
// PHASE-SPLIT: P1 {8 ds_read (A mf0-3 + B nf0-3) || 2 A-gloads -> bar ->
// lgkm0 -> prio+16 MFMA -> bar}, P2 {4 ds_read (A mf4-7) || 2 B-gloads ->
// bar -> lgkm0 -> prio+16 MFMA -> vmcnt(4) -> bar}. Ring-3 both matrices.
__global__ __launch_bounds__(512, 2) void gemm_o(const unsigned short* __restrict__ A,
                                                 const unsigned short* __restrict__ B,
                                                 float* __restrict__ C) {
  const int K = 4096, N = 4096, nt = 128;
  __shared__ unsigned short AS[3][8192];   // 48 KB: [128 prow][64 sh] per slot
  __shared__ unsigned short BS[3][8192];   // 48 KB
  const int tid  = threadIdx.x;
  const int lane = tid & 63;
  const int wave = tid >> 6;
  const int m16  = lane & 15;
  const int quad = lane >> 4;
  const int wm   = wave >> 2;   // 0..1: rows wm*128..+127
  const int wn   = wave & 3;    // 0..3: cols wn*64..+63

  const int gx = 16;
  const int orig = blockIdx.y * gx + blockIdx.x;
  const int swz = (orig & 7) * 32 + (orig >> 3);
  const long rowBase = (long)(swz / gx) * 256;
  const long colBase = (long)(swz % gx) * 256;

  // frag read offsets (shorts): p&7 == m16>>1 for all mf/nf
  const int slot8 = ((quad + 4 * (m16 & 1)) ^ (m16 >> 1)) * 8;
  const int aob = (wm * 64 + (m16 >> 1)) * 64 + slot8;   // + mf*512
  const int bob = (wn * 32 + (m16 >> 1)) * 64 + slot8;   // + nf*512

  // staging source (inverse of packed swizzle)
  const long Kl = K;
  const int z = (tid & 7) ^ ((tid >> 3) & 7);
  const long srow = 2 * (tid >> 3) + (z >> 2);
  const int sk = (z & 3) * 8;
  const unsigned short* oA = A + (rowBase + srow) * Kl + sk;
  const unsigned short* oB = B + (colBase + srow) * Kl + sk;
  const int dofs = wave * 512;

#define OSTG_A(sl_, ko_) { GLOAD_LDS16(oA + (ko_),            &AS[sl_][dofs]);         \
                           GLOAD_LDS16(oA + (ko_) + 128 * Kl, &AS[sl_][4096 + dofs]); }
#define OSTG_B(sl_, ko_) { GLOAD_LDS16(oB + (ko_),            &BS[sl_][dofs]);         \
                           GLOAD_LDS16(oB + (ko_) + 128 * Kl, &BS[sl_][4096 + dofs]); }

  f32x4 acc[8][4] = {};   // [mf][nf]

  OSTG_A(0, 0);  OSTG_B(0, 0);
  OSTG_A(1, 32); OSTG_B(1, 32);
  asm volatile("s_waitcnt vmcnt(4)" ::: "memory");
  __builtin_amdgcn_s_barrier();

  for (int g = 0; g < 43; ++g) {
#pragma unroll
    for (int u = 0; u < 3; ++u) {
      const int t = g * 3 + u;
      if (t < nt) {
        const bool doStage = (t + 2) < nt;
        const long kn = (long)(t + 2) * 32;
        bf16x8 af[4], bfr[4];

        // ---------- P1: A mf0-3 + B nf0-3 (8 ds_read) || 2 A-gloads ----------
#pragma unroll
        for (int nf = 0; nf < 4; ++nf)
          bfr[nf] = *(const bf16x8*)(&BS[u][bob + nf * 512]);
#pragma unroll
        for (int mf = 0; mf < 4; ++mf)
          af[mf] = *(const bf16x8*)(&AS[u][aob + mf * 512]);
        if (doStage) OSTG_A((u + 2) % 3, kn);
        __builtin_amdgcn_s_barrier();
        asm volatile("s_waitcnt lgkmcnt(0)" ::: "memory");
        __builtin_amdgcn_s_setprio(1);
#pragma unroll
        for (int mf = 0; mf < 4; ++mf)
#pragma unroll
          for (int nf = 0; nf < 4; ++nf)
            acc[mf][nf] = __builtin_amdgcn_mfma_f32_16x16x32_bf16(af[mf], bfr[nf], acc[mf][nf], 0, 0, 0);
        __builtin_amdgcn_s_setprio(0);
        __builtin_amdgcn_s_barrier();

        // ---------- P2: A mf4-7 (4 ds_read) || 2 B-gloads, vmcnt(4) ----------
#pragma unroll
        for (int mf = 0; mf < 4; ++mf)
          af[mf] = *(const bf16x8*)(&AS[u][aob + (4 + mf) * 512]);
        if (doStage) OSTG_B((u + 2) % 3, kn);
        __builtin_amdgcn_s_barrier();
        asm volatile("s_waitcnt lgkmcnt(0)" ::: "memory");
        __builtin_amdgcn_s_setprio(1);
#pragma unroll
        for (int mf = 0; mf < 4; ++mf)
#pragma unroll
          for (int nf = 0; nf < 4; ++nf)
            acc[4 + mf][nf] = __builtin_amdgcn_mfma_f32_16x16x32_bf16(af[mf], bfr[nf], acc[4 + mf][nf], 0, 0, 0);
        __builtin_amdgcn_s_setprio(0);
        if (doStage)         asm volatile("s_waitcnt vmcnt(4)" ::: "memory");
        else if (t + 1 < nt) asm volatile("s_waitcnt vmcnt(0)" ::: "memory");
        __builtin_amdgcn_s_barrier();
      }
    }
  }

#pragma unroll
  for (int mf = 0; mf < 8; ++mf)
#pragma unroll
    for (int nf = 0; nf < 4; ++nf) {
      long c = colBase + wn * 64 + nf * 16 + m16;
#pragma unroll
      for (int reg = 0; reg < 4; ++reg) {
        long row = rowBase + wm * 128 + mf * 16 + quad * 4 + reg;
        C[row * N + c] = acc[mf][nf][reg];
      }
    }
}

// ---------------- Flash attention (causal, GQA), bf16 MFMA ----------------
// T14 async-STAGE: K/V double-buffered; issue kt+1's K gloads + V reg loads
// right after QK^T(kt); drain + scatter after PV(kt). One __syncthreads/tile.
#define ATT_SCALE_L2 0.12754227022f  // (1/sqrt(128)) * log2(e)
__global__ __launch_bounds__(256) void attn_k(const unsigned short* __restrict__ Qp,
                                              const unsigned short* __restrict__ Kp,
                                              const unsigned short* __restrict__ Vp,
                                              unsigned short* __restrict__ Op) {
  const int pr = blockIdx.x, h = blockIdx.y, b = blockIdx.z;
  const int kvh = h >> 2;
  const int tid = threadIdx.x, wave = tid >> 6, lane = tid & 63;
  const int m16 = lane & 15, quad = lane >> 4;

  __shared__ unsigned short Ks[2][64][128];   // dbuf [key][d], xor swizzle
  __shared__ unsigned short Vt[2][128][64];   // dbuf [d][key], additive rotation
  __shared__ unsigned short Ps[4][32][64];    // per-wave P

  const unsigned short* Kh = Kp + (long)(b * SEQ) * (NKVH * HDIM) + kvh * HDIM;
  const unsigned short* Vh = Vp + (long)(b * SEQ) * (NKVH * HDIM) + kvh * HDIM;

#define STAGE_K(ktv, bufp) {                                               \
    _Pragma("unroll")                                                      \
    for (int it_ = 0; it_ < 4; ++it_) {                                    \
      int c_ = it_ * 256 + tid;                                            \
      int row_ = c_ >> 4, psg_ = c_ & 15;                                  \
      int sg_ = (psg_ & 8) | ((psg_ & 7) ^ (row_ & 7));                    \
      GLOAD_LDS16(Kh + ((long)(ktv) * 64 + row_) * (NKVH * HDIM) + sg_ * 8,\
                  ((unsigned short*)(bufp)) + (it_ * 256 + wave * 64) * 8);\
    } }

#define LOAD_V(ktv, dvv) {                                                 \
    _Pragma("unroll")                                                      \
    for (int it_ = 0; it_ < 4; ++it_)                                      \
      dvv[it_] = *(const uint4*)(Vh + ((long)(ktv) * 64 + lane) * (NKVH * HDIM) + (it_ * 4 + wave) * 8); }

#define SCATTER_V(bufp, dvv) {                                             \
    _Pragma("unroll")                                                      \
    for (int it_ = 0; it_ < 4; ++it_) {                                    \
      const unsigned short* pv_ = (const unsigned short*)&dvv[it_];        \
      int seg_ = it_ * 4 + wave;                                           \
      _Pragma("unroll")                                                    \
      for (int e_ = 0; e_ < 8; ++e_) {                                     \
        int d_ = seg_ * 8 + e_;                                            \
        (bufp)[d_][((((lane >> 3) + d_) & 7) * 8) + (lane & 7)] = pv_[e_]; \
      } } }

  for (int pass = 0; pass < 2; ++pass) {
    const int qt = pass ? pr : (7 - pr);
    const int qbase = qt * 128;
    const int wq_lo = qbase + wave * 32;

    bf16x8 qa[2][4];
#pragma unroll
    for (int i = 0; i < 2; ++i) {
      const unsigned short* qrow =
          Qp + (long)(b * SEQ + wq_lo + i * 16 + m16) * (NHQ * HDIM) + h * HDIM;
#pragma unroll
      for (int kk = 0; kk < 4; ++kk)
        qa[i][kk] = *(const bf16x8*)(qrow + kk * 32 + quad * 8);
    }

    f32x4 o[2][8] = {};
    float mrow[2][4], lrow[2][4];
#pragma unroll
    for (int i = 0; i < 2; ++i)
#pragma unroll
      for (int r = 0; r < 4; ++r) { mrow[i][r] = -1e30f; lrow[i][r] = 0.f; }

    const int nkt = qt * 2 + 2;

    {  // prologue: stage kt=0 into buffer 0
      STAGE_K(0, Ks[0]);
      uint4 dv[4];
      LOAD_V(0, dv);
      asm volatile("s_waitcnt vmcnt(0)" ::: "memory");
      SCATTER_V(Vt[0], dv);
    }
    __syncthreads();

    for (int kt = 0; kt < nkt; ++kt) {
      const int cb = kt & 1;
      const bool active = (kt * 64) <= (wq_lo + 31);
      const bool more = (kt + 1) < nkt;

      f32x4 s4[2][4] = {};
      if (active) {
        __builtin_amdgcn_s_setprio(1);
#pragma unroll
        for (int kk = 0; kk < 4; ++kk) {
          bf16x8 kbf[4];
#pragma unroll
          for (int j = 0; j < 4; ++j) {
            int row = j * 16 + m16;
            int cl = kk * 4 + quad;
            int ps = (cl & 8) | ((cl & 7) ^ (row & 7));
            kbf[j] = *(const bf16x8*)(&Ks[cb][row][ps * 8]);
          }
#pragma unroll
          for (int i = 0; i < 2; ++i)
#pragma unroll
            for (int j = 0; j < 4; ++j)
              s4[i][j] = __builtin_amdgcn_mfma_f32_16x16x32_bf16(qa[i][kk], kbf[j], s4[i][j], 0, 0, 0);
        }
        __builtin_amdgcn_s_setprio(0);
      }

      // ---- T14: issue next tile's loads early; HBM latency hides under softmax+PV
      uint4 dv[4];
      if (more) {
        STAGE_K(kt + 1, Ks[cb ^ 1]);
        LOAD_V(kt + 1, dv);
      }
      asm volatile("" ::: "memory");

      if (active) {
        const bool full = (kt * 64 + 63) <= wq_lo;
#pragma unroll
        for (int i = 0; i < 2; ++i) {
#pragma unroll
          for (int r = 0; r < 4; ++r) {
            const int qrow = i * 16 + quad * 4 + r;
            const int qi = qbase + wave * 32 + qrow;
            float v[4];
#pragma unroll
            for (int j = 0; j < 4; ++j) {
              v[j] = s4[i][j][r] * ATT_SCALE_L2;
              if (!full && (kt * 64 + j * 16 + m16 > qi)) v[j] = -1e30f;
            }
            float mx = fmaxf(fmaxf(v[0], v[1]), fmaxf(v[2], v[3]));
            mx = fmaxf(mx, __shfl_xor(mx, 1));
            mx = fmaxf(mx, __shfl_xor(mx, 2));
            mx = fmaxf(mx, __shfl_xor(mx, 4));
            mx = fmaxf(mx, __shfl_xor(mx, 8));
            float mold = mrow[i][r];
            float mnew = fmaxf(mold, mx);
            float alpha = exp2f(mold - mnew);
            float rs = 0.f;
#pragma unroll
            for (int j = 0; j < 4; ++j) {
              float pj = exp2f(v[j] - mnew);
              rs += pj;
              int col = j * 16 + m16;
              Ps[wave][qrow][((((col >> 3) + qrow) & 7) * 8) + (col & 7)] = f2bf(pj);
            }
            rs += __shfl_xor(rs, 1); rs += __shfl_xor(rs, 2);
            rs += __shfl_xor(rs, 4); rs += __shfl_xor(rs, 8);
            lrow[i][r] = lrow[i][r] * alpha + rs;
            mrow[i][r] = mnew;
#pragma unroll
            for (int n = 0; n < 8; ++n) o[i][n][r] *= alpha;
          }
        }
        __builtin_amdgcn_s_setprio(1);
#pragma unroll
        for (int kk = 0; kk < 2; ++kk) {
          bf16x8 pa[2], vb[8];
#pragma unroll
          for (int i = 0; i < 2; ++i) {
            int row = i * 16 + m16;
            pa[i] = *(const bf16x8*)(&Ps[wave][row][(((kk * 4 + quad) + row) & 7) * 8]);
          }
#pragma unroll
          for (int n = 0; n < 8; ++n) {
            int row = n * 16 + m16;
            vb[n] = *(const bf16x8*)(&Vt[cb][row][(((kk * 4 + quad) + row) & 7) * 8]);
          }
#pragma unroll
          for (int i = 0; i < 2; ++i)
#pragma unroll
            for (int n = 0; n < 8; ++n)
              o[i][n] = __builtin_amdgcn_mfma_f32_16x16x32_bf16(pa[i], vb[n], o[i][n], 0, 0, 0);
        }
        __builtin_amdgcn_s_setprio(0);
      }

      if (more) {
        asm volatile("s_waitcnt vmcnt(0)" ::: "memory");
        SCATTER_V(Vt[cb ^ 1], dv);
      }
      __syncthreads();
    }

#pragma unroll
    for (int i = 0; i < 2; ++i) {
#pragma unroll
      for (int r = 0; r < 4; ++r) {
        float inv = 1.0f / lrow[i][r];
        unsigned short* orow =
            Op + (long)(b * SEQ + wq_lo + i * 16 + quad * 4 + r) * (NHQ * HDIM) + h * HDIM;
#pragma unroll
        for (int n = 0; n < 8; ++n)
          orow[n * 16 + m16] = f2bf(o[i][n][r] * inv);
      }
    }
  }
}

// ---------------- launch ----------------
extern "C" void kernel_launch(void* const* d_in, const int* in_sizes, int n_in,
                              void* d_out, int out_size, void* d_ws, size_t ws_size,
                              hipStream_t stream) {
  (void)in_sizes; (void)n_in; (void)out_size; (void)ws_size;
  const float* x  = (const float*)d_in[0];
  const int* pos  = (const int*)d_in[1];
  const float* wq = (const float*)d_in[3];
  const float* wk = (const float*)d_in[4];
  const float* wv = (const float*)d_in[5];
  const float* wo = (const float*)d_in[6];
  float* out = (float*)d_out;

  char* ws = (char*)d_ws;
  unsigned short* xb    = (unsigned short*)(ws);                   // 32MB bf16 x
  unsigned short* wqkv  = (unsigned short*)(ws + (32ll << 20));    // 48MB bf16 [wq;wk;wv]
  unsigned short* wob   = (unsigned short*)(ws + (80ll << 20));    // 32MB bf16 wo
  unsigned short* qr    = (unsigned short*)(ws + (112ll << 20));   // 32MB q roped bf16
  unsigned short* kr    = (unsigned short*)(ws + (144ll << 20));   // 8MB  k roped bf16
  unsigned short* vb_   = (unsigned short*)(ws + (152ll << 20));   // 8MB  v bf16
  unsigned short* ao    = (unsigned short*)(ws + (160ll << 20));   // 32MB attn out bf16

  cast_all_k<<<57344, 256, 0, stream>>>(x, wq, wk, wv, wo, xb, wqkv, wob);
  gemm_qkv<<<dim3(48, 16), 512, 0, stream>>>(xb, wqkv, pos, qr, kr, vb_);
  attn_k<<<dim3(4, 32, 4), 256, 0, stream>>>(qr, kr, vb_, ao);
  gemm_o<<<dim3(16, 16), 512, 0, stream>>>(ao, wob, out);
}